// Round 3
// baseline (222.090 us; speedup 1.0000x reference)
//
#include <hip/hip_runtime.h>
#include <stdint.h>

#define B_ROWS 4096
#define D_DIM  512
#define N_TOT  8192
#define TEMP_INV 2.0f   // 1/0.5
#define NB     64       // N_TOT / 128 tiles per dim
#define NTRI   2080     // NB*(NB+1)/2
#define KT_N   (D_DIM / 32)  // 16 K-steps

typedef __bf16 bf16x8 __attribute__((ext_vector_type(8)));
typedef float  f32x4  __attribute__((ext_vector_type(4)));
typedef unsigned short ushort8 __attribute__((ext_vector_type(8)));

__device__ __forceinline__ unsigned short f2bf(float f) {
    union { float f; unsigned int u; } c; c.f = f;
    unsigned int u = c.u;
    return (unsigned short)((u + 0x7fffu + ((u >> 16) & 1u)) >> 16);
}

// ------- kernel 1: fused L2-normalize (write bf16 z) + positive-pair dot -------
// one wave per pair k; also zeroes rowsum (replaces hipMemsetAsync dispatch)
__global__ __launch_bounds__(256) void normpos_kernel(
    const float* __restrict__ xi, const float* __restrict__ xj,
    unsigned short* __restrict__ z, float* __restrict__ pos,
    float* __restrict__ rowsum) {
    if (blockIdx.x < N_TOT / 256) rowsum[blockIdx.x * 256 + threadIdx.x] = 0.f;
    const int wid  = threadIdx.x >> 6;
    const int lane = threadIdx.x & 63;
    const int k    = blockIdx.x * 4 + wid;
    const float4* a4 = (const float4*)(xi + (size_t)k * D_DIM);
    const float4* b4 = (const float4*)(xj + (size_t)k * D_DIM);
    float4 va0 = a4[2 * lane], va1 = a4[2 * lane + 1];
    float4 vb0 = b4[2 * lane], vb1 = b4[2 * lane + 1];
    float ssa = va0.x*va0.x + va0.y*va0.y + va0.z*va0.z + va0.w*va0.w
              + va1.x*va1.x + va1.y*va1.y + va1.z*va1.z + va1.w*va1.w;
    float ssb = vb0.x*vb0.x + vb0.y*vb0.y + vb0.z*vb0.z + vb0.w*vb0.w
              + vb1.x*vb1.x + vb1.y*vb1.y + vb1.z*vb1.z + vb1.w*vb1.w;
    float dot = va0.x*vb0.x + va0.y*vb0.y + va0.z*vb0.z + va0.w*vb0.w
              + va1.x*vb1.x + va1.y*vb1.y + va1.z*vb1.z + va1.w*vb1.w;
    #pragma unroll
    for (int m = 32; m >= 1; m >>= 1) {
        ssa += __shfl_xor(ssa, m);
        ssb += __shfl_xor(ssb, m);
        dot += __shfl_xor(dot, m);
    }
    const float rna = 1.0f / fmaxf(sqrtf(ssa), 1e-12f);
    const float rnb = 1.0f / fmaxf(sqrtf(ssb), 1e-12f);
    float av[8] = {va0.x, va0.y, va0.z, va0.w, va1.x, va1.y, va1.z, va1.w};
    float bv[8] = {vb0.x, vb0.y, vb0.z, vb0.w, vb1.x, vb1.y, vb1.z, vb1.w};
    union { ushort8 v; unsigned short s[8]; } oa, ob;
    #pragma unroll
    for (int i = 0; i < 8; ++i) {
        oa.s[i] = f2bf(av[i] * rna);
        ob.s[i] = f2bf(bv[i] * rnb);
    }
    *(ushort8*)(z + (size_t)k * D_DIM + lane * 8) = oa.v;
    *(ushort8*)(z + (size_t)(k + B_ROWS) * D_DIM + lane * 8) = ob.v;
    if (lane == 0) pos[k] = dot * rna * rnb;
}

// -------- kernel 2: symmetric fused Gram-row-sum over upper-triangular tiles --------
// v3: NO LDS staging. z (8 MB bf16) is L2/L3-resident; each wave loads its MFMA
// fragments directly from global into registers (every 64B cacheline fetched is
// fully consumed: lanes l, l+16, l+32, l+48 read the 4 16B chunks of one row's
// 64B k-slice). No barriers in the K-loop; register ping-pong gives 2-deep load
// pipelining; wave independence + occupancy hides L2 latency. LDS only holds the
// 128-row/col partial sums.
__global__ __launch_bounds__(256) void simrow_kernel(
    const unsigned short* __restrict__ z, float* __restrict__ rowsum) {
    __shared__ float rsum[128];
    __shared__ float csum[128];
    const int tid  = threadIdx.x;
    const int lane = tid & 63;
    const int wid  = tid >> 6;

    // XCD-chunked block swizzle (T1): NTRI % 8 == 0 -> bijective.
    // Consecutive original ids (same bi, adjacent bj -> shared A panel) land on
    // the same XCD's L2.
    const int t0 = (blockIdx.x & 7) * (NTRI / 8) + (blockIdx.x >> 3);

    // map linear id -> upper-triangular (bi, bj), bi <= bj
    int bi = (int)(NB + 0.5f - sqrtf((NB + 0.5f) * (NB + 0.5f) - 2.0f * t0));
    if (bi < 0) bi = 0;
    if (bi > NB - 1) bi = NB - 1;
    while (bi > 0 && (bi * NB - bi * (bi - 1) / 2) > t0) --bi;
    while ((bi + 1) * NB - (bi + 1) * bi / 2 <= t0) ++bi;
    const int bj = bi + (t0 - (bi * NB - bi * (bi - 1) / 2));
    const int row0 = bi * 128;
    const int col0 = bj * 128;
    const bool diag = (bi == bj);

    if (tid < 128) { rsum[tid] = 0.f; csum[tid] = 0.f; }

    const int wr = wid >> 1, wc = wid & 1;
    const int ml = lane & 15;   // row within 16x16 fragment
    const int kq = lane >> 4;   // k-chunk 0..3 (8 bf16 = 16B each)

    f32x4 acc[4][4] = {};

    // per-lane fragment base pointers; per-kt offsets fold into load immediates
    const unsigned short* ap[4];
    const unsigned short* bp[4];
    #pragma unroll
    for (int mi = 0; mi < 4; ++mi)
        ap[mi] = z + (size_t)(row0 + wr * 64 + mi * 16 + ml) * D_DIM + kq * 8;
    #pragma unroll
    for (int ni = 0; ni < 4; ++ni)
        bp[ni] = z + (size_t)(col0 + wc * 64 + ni * 16 + ml) * D_DIM + kq * 8;

    // register ping-pong (all-static indexing, no barriers)
    bf16x8 a0[4], b0[4], a1[4], b1[4];
    #pragma unroll
    for (int i = 0; i < 4; ++i) {
        a0[i] = *(const bf16x8*)(ap[i]);
        b0[i] = *(const bf16x8*)(bp[i]);
    }
    #pragma unroll
    for (int kt = 0; kt < KT_N; kt += 2) {
        if (kt + 1 < KT_N) {
            #pragma unroll
            for (int i = 0; i < 4; ++i) {
                a1[i] = *(const bf16x8*)(ap[i] + (kt + 1) * 32);
                b1[i] = *(const bf16x8*)(bp[i] + (kt + 1) * 32);
            }
        }
        #pragma unroll
        for (int mi = 0; mi < 4; ++mi)
            #pragma unroll
            for (int ni = 0; ni < 4; ++ni)
                acc[mi][ni] = __builtin_amdgcn_mfma_f32_16x16x32_bf16(
                    a0[mi], b0[ni], acc[mi][ni], 0, 0, 0);
        if (kt + 2 < KT_N) {
            #pragma unroll
            for (int i = 0; i < 4; ++i) {
                a0[i] = *(const bf16x8*)(ap[i] + (kt + 2) * 32);
                b0[i] = *(const bf16x8*)(bp[i] + (kt + 2) * 32);
            }
        }
        #pragma unroll
        for (int mi = 0; mi < 4; ++mi)
            #pragma unroll
            for (int ni = 0; ni < 4; ++ni)
                acc[mi][ni] = __builtin_amdgcn_mfma_f32_16x16x32_bf16(
                    a1[mi], b1[ni], acc[mi][ni], 0, 0, 0);
    }

    // ensure rsum/csum zero-init is visible before epilogue atomics
    __syncthreads();

    // epilogue: e = exp(2*sim), mask diagonal; row sums always, col sums if off-diag
    const int quad = lane >> 4;
    const int cl   = lane & 15;
    float colacc[4] = {0.f, 0.f, 0.f, 0.f};
    #pragma unroll
    for (int mi = 0; mi < 4; ++mi) {
        #pragma unroll
        for (int r = 0; r < 4; ++r) {
            const int lrow = wr * 64 + mi * 16 + quad * 4 + r;
            const int irow = row0 + lrow;
            float s = 0.f;
            #pragma unroll
            for (int ni = 0; ni < 4; ++ni) {
                const int jcol = col0 + wc * 64 + ni * 16 + cl;
                float e = __expf(TEMP_INV * acc[mi][ni][r]);
                e = (irow == jcol) ? 0.f : e;
                s += e;
                colacc[ni] += e;
            }
            s += __shfl_xor(s, 1);
            s += __shfl_xor(s, 2);
            s += __shfl_xor(s, 4);
            s += __shfl_xor(s, 8);
            if (cl == 0) atomicAdd(&rsum[lrow], s);
        }
    }
    if (!diag) {
        #pragma unroll
        for (int ni = 0; ni < 4; ++ni) {
            float c = colacc[ni];
            c += __shfl_xor(c, 16);
            c += __shfl_xor(c, 32);
            if (quad == 0) atomicAdd(&csum[wc * 64 + ni * 16 + cl], c);
        }
    }
    __syncthreads();
    if (tid < 128) {
        atomicAdd(&rowsum[row0 + tid], rsum[tid]);
        if (!diag) atomicAdd(&rowsum[col0 + tid], csum[tid]);
    }
}

// ---------------- kernel 3: finalize scalar loss ----------------
__global__ __launch_bounds__(256) void finalize_kernel(
    const float* __restrict__ rowsum, const float* __restrict__ pos,
    float* __restrict__ out) {
    const int t = threadIdx.x;
    float s = 0.f;
    for (int i = t; i < N_TOT; i += 256) s += logf(rowsum[i]);
    float p = 0.f;
    for (int i = t; i < B_ROWS; i += 256) p += pos[i];
    #pragma unroll
    for (int m = 32; m >= 1; m >>= 1) {
        s += __shfl_xor(s, m);
        p += __shfl_xor(p, m);
    }
    __shared__ float ws[4], wp[4];
    if ((t & 63) == 0) { ws[t >> 6] = s; wp[t >> 6] = p; }
    __syncthreads();
    if (t == 0) {
        float tot = ws[0] + ws[1] + ws[2] + ws[3];
        float ptot = wp[0] + wp[1] + wp[2] + wp[3];
        // loss = mean(log denom) - (2*posSum)/(temp*N)
        out[0] = tot / (float)N_TOT - ptot * (2.0f * TEMP_INV / (float)N_TOT);
    }
}

extern "C" void kernel_launch(void* const* d_in, const int* in_sizes, int n_in,
                              void* d_out, int out_size, void* d_ws, size_t ws_size,
                              hipStream_t stream) {
    const float* xi = (const float*)d_in[0];
    const float* xj = (const float*)d_in[1];
    float* out = (float*)d_out;
    char* ws = (char*)d_ws;

    unsigned short* z = (unsigned short*)ws;                       // 8 MB bf16
    float* rowsum = (float*)(ws + (size_t)N_TOT * D_DIM * 2);      // 32 KB
    float* pos = rowsum + N_TOT;                                   // 16 KB

    normpos_kernel<<<B_ROWS / 4, 256, 0, stream>>>(xi, xj, z, pos, rowsum);
    simrow_kernel<<<NTRI, 256, 0, stream>>>(z, rowsum);
    finalize_kernel<<<1, 256, 0, stream>>>(rowsum, pos, out);
}

// Round 4
// 139.809 us; speedup vs baseline: 1.5885x; 1.5885x over previous
//
#include <hip/hip_runtime.h>
#include <stdint.h>

#define B_ROWS 4096
#define D_DIM  512
#define N_TOT  8192
#define TEMP_INV 2.0f   // 1/0.5
#define NB     64       // N_TOT / 128 tiles per dim
#define NTRI   2080     // NB*(NB+1)/2
#define KT_N   (D_DIM / 32)  // 16 K-steps

typedef __bf16 bf16x8 __attribute__((ext_vector_type(8)));
typedef float  f32x4  __attribute__((ext_vector_type(4)));
typedef unsigned short ushort8 __attribute__((ext_vector_type(8)));

// counted vmcnt wait that the compiler cannot reorder memory ops across
#define VM_WAIT(N) asm volatile("s_waitcnt vmcnt(" #N ")" ::: "memory")
#define LGKM0()    asm volatile("s_waitcnt lgkmcnt(0)" ::: "memory")
#define BAR()      do { asm volatile("" ::: "memory"); \
                        __builtin_amdgcn_s_barrier();  \
                        asm volatile("" ::: "memory"); } while (0)

__device__ __forceinline__ unsigned short f2bf(float f) {
    union { float f; unsigned int u; } c; c.f = f;
    unsigned int u = c.u;
    return (unsigned short)((u + 0x7fffu + ((u >> 16) & 1u)) >> 16);
}

// async global->LDS, 16B per lane. LDS dest is wave-uniform base + lane*16.
__device__ __forceinline__ void gl_lds16(const void* g, void* l) {
    __builtin_amdgcn_global_load_lds(
        (__attribute__((address_space(1))) void*)(uintptr_t)g,
        (__attribute__((address_space(3))) void*)(uintptr_t)l,
        16, 0, 0);
}

// ------- kernel 1: fused L2-normalize (write bf16 z) + positive-pair dot -------
// one wave per pair k; also zeroes rowsum (replaces hipMemsetAsync dispatch)
__global__ __launch_bounds__(256) void normpos_kernel(
    const float* __restrict__ xi, const float* __restrict__ xj,
    unsigned short* __restrict__ z, float* __restrict__ pos,
    float* __restrict__ rowsum) {
    if (blockIdx.x < N_TOT / 256) rowsum[blockIdx.x * 256 + threadIdx.x] = 0.f;
    const int wid  = threadIdx.x >> 6;
    const int lane = threadIdx.x & 63;
    const int k    = blockIdx.x * 4 + wid;
    const float4* a4 = (const float4*)(xi + (size_t)k * D_DIM);
    const float4* b4 = (const float4*)(xj + (size_t)k * D_DIM);
    float4 va0 = a4[2 * lane], va1 = a4[2 * lane + 1];
    float4 vb0 = b4[2 * lane], vb1 = b4[2 * lane + 1];
    float ssa = va0.x*va0.x + va0.y*va0.y + va0.z*va0.z + va0.w*va0.w
              + va1.x*va1.x + va1.y*va1.y + va1.z*va1.z + va1.w*va1.w;
    float ssb = vb0.x*vb0.x + vb0.y*vb0.y + vb0.z*vb0.z + vb0.w*vb0.w
              + vb1.x*vb1.x + vb1.y*vb1.y + vb1.z*vb1.z + vb1.w*vb1.w;
    float dot = va0.x*vb0.x + va0.y*vb0.y + va0.z*vb0.z + va0.w*vb0.w
              + va1.x*vb1.x + va1.y*vb1.y + va1.z*vb1.z + va1.w*vb1.w;
    #pragma unroll
    for (int m = 32; m >= 1; m >>= 1) {
        ssa += __shfl_xor(ssa, m);
        ssb += __shfl_xor(ssb, m);
        dot += __shfl_xor(dot, m);
    }
    const float rna = 1.0f / fmaxf(sqrtf(ssa), 1e-12f);
    const float rnb = 1.0f / fmaxf(sqrtf(ssb), 1e-12f);
    float av[8] = {va0.x, va0.y, va0.z, va0.w, va1.x, va1.y, va1.z, va1.w};
    float bv[8] = {vb0.x, vb0.y, vb0.z, vb0.w, vb1.x, vb1.y, vb1.z, vb1.w};
    union { ushort8 v; unsigned short s[8]; } oa, ob;
    #pragma unroll
    for (int i = 0; i < 8; ++i) {
        oa.s[i] = f2bf(av[i] * rna);
        ob.s[i] = f2bf(bv[i] * rnb);
    }
    *(ushort8*)(z + (size_t)k * D_DIM + lane * 8) = oa.v;
    *(ushort8*)(z + (size_t)(k + B_ROWS) * D_DIM + lane * 8) = ob.v;
    if (lane == 0) pos[k] = dot * rna * rnb;
}

// -------- kernel 2: symmetric fused Gram-row-sum over upper-triangular tiles --------
// v4: v0 structure (LDS staging via global_load_lds, 128x128 tile, 2x2 waves,
// XOR-swizzled k-chunk slots) + double-buffered LDS with COUNTED vmcnt across raw
// s_barriers (T4): tile k+1's 4 loads/wave stay in flight through iteration k's
// compute, so the barrier no longer drains the prefetch (the ~75% stall in v0).
// Diagonal blocks stage B redundantly so every stage is exactly 4 VMEM ops/wave,
// keeping the vmcnt immediates uniform.
__global__ __launch_bounds__(256) void simrow_kernel(
    const unsigned short* __restrict__ z, float* __restrict__ rowsum) {
    __shared__ unsigned short As[2][128 * 32];  // 2 x 8 KB
    __shared__ unsigned short Bs[2][128 * 32];  // 2 x 8 KB
    __shared__ float rsum[128];
    __shared__ float csum[128];
    const int tid  = threadIdx.x;
    const int lane = tid & 63;
    const int wid  = tid >> 6;

    // XCD-chunked block swizzle (T1): NTRI % 8 == 0 -> bijective
    const int t0 = (blockIdx.x & 7) * (NTRI / 8) + (blockIdx.x >> 3);

    // map linear id -> upper-triangular (bi, bj), bi <= bj
    int bi = (int)(NB + 0.5f - sqrtf((NB + 0.5f) * (NB + 0.5f) - 2.0f * t0));
    if (bi < 0) bi = 0;
    if (bi > NB - 1) bi = NB - 1;
    while (bi > 0 && (bi * NB - bi * (bi - 1) / 2) > t0) --bi;
    while ((bi + 1) * NB - (bi + 1) * bi / 2 <= t0) ++bi;
    const int bj = bi + (t0 - (bi * NB - bi * (bi - 1) / 2));
    const int row0 = bi * 128;
    const int col0 = bj * 128;
    const bool diag = (bi == bj);

    if (tid < 128) { rsum[tid] = 0.f; csum[tid] = 0.f; }

    const int wr = wid >> 1, wc = wid & 1;
    f32x4 acc[4][4] = {};

    // staging: lane -> (row = wid*16 + (lane>>2), slot = lane&3)
    // slot c stores global k-chunk c ^ ((row>>1)&3); here (row>>1)&3 == (lane>>3)&3
    const int srow = wid * 16 + (lane >> 2);
    const int skc  = ((lane & 3) ^ ((lane >> 3) & 3)) * 8;
    const unsigned short* gA = z + (size_t)(row0 + srow) * D_DIM + skc;
    const unsigned short* gB = z + (size_t)(col0 + srow) * D_DIM + skc;

    // exactly 4 VMEM ops per wave per stage (A x2, B x2) -> vmcnt unit = 4
    auto stage = [&](int buf, int kt) {
        const int k0 = kt * 32;
        #pragma unroll
        for (int t = 0; t < 2; ++t) {
            gl_lds16(gA + (size_t)(t * 64) * D_DIM + k0, &As[buf][t * 2048 + wid * 512]);
            gl_lds16(gB + (size_t)(t * 64) * D_DIM + k0, &Bs[buf][t * 2048 + wid * 512]);
        }
    };

    const int kqi = lane >> 4;         // desired global k-chunk
    const int ml  = lane & 15;
    const int sw  = (ml >> 1) & 3;     // swizzle term for this row parity
    const int slot = (kqi ^ sw) * 8;

    // prologue: two tiles in flight
    stage(0, 0);
    stage(1, 1);

    int cur = 0;
    for (int kt = 0; kt < KT_N - 1; ++kt) {
        VM_WAIT(4);   // tile kt landed; tile kt+1's 4 loads remain in flight
        BAR();
        const unsigned short* Asrc = &As[cur][0];
        const unsigned short* Bsrc = &Bs[cur][0];
        bf16x8 af[4], bfr[4];
        #pragma unroll
        for (int mi = 0; mi < 4; ++mi)
            af[mi] = *(const bf16x8*)&Asrc[(wr * 64 + mi * 16 + ml) * 32 + slot];
        #pragma unroll
        for (int ni = 0; ni < 4; ++ni)
            bfr[ni] = *(const bf16x8*)&Bsrc[(wc * 64 + ni * 16 + ml) * 32 + slot];
        #pragma unroll
        for (int mi = 0; mi < 4; ++mi)
            #pragma unroll
            for (int ni = 0; ni < 4; ++ni)
                acc[mi][ni] = __builtin_amdgcn_mfma_f32_16x16x32_bf16(
                    af[mi], bfr[ni], acc[mi][ni], 0, 0, 0);
        LGKM0();      // ds_reads of buf[cur] retired before buffer is released
        BAR();
        if (kt + 2 < KT_N) stage(cur, kt + 2);  // flies through iteration kt+1
        cur ^= 1;
    }
    // peeled last iteration: drain everything
    {
        VM_WAIT(0);
        BAR();
        const unsigned short* Asrc = &As[cur][0];
        const unsigned short* Bsrc = &Bs[cur][0];
        bf16x8 af[4], bfr[4];
        #pragma unroll
        for (int mi = 0; mi < 4; ++mi)
            af[mi] = *(const bf16x8*)&Asrc[(wr * 64 + mi * 16 + ml) * 32 + slot];
        #pragma unroll
        for (int ni = 0; ni < 4; ++ni)
            bfr[ni] = *(const bf16x8*)&Bsrc[(wc * 64 + ni * 16 + ml) * 32 + slot];
        #pragma unroll
        for (int mi = 0; mi < 4; ++mi)
            #pragma unroll
            for (int ni = 0; ni < 4; ++ni)
                acc[mi][ni] = __builtin_amdgcn_mfma_f32_16x16x32_bf16(
                    af[mi], bfr[ni], acc[mi][ni], 0, 0, 0);
    }

    // epilogue: e = exp(2*sim), mask diagonal; row sums always, col sums if off-diag
    const int quad = lane >> 4;
    const int cl   = lane & 15;
    float colacc[4] = {0.f, 0.f, 0.f, 0.f};
    #pragma unroll
    for (int mi = 0; mi < 4; ++mi) {
        #pragma unroll
        for (int r = 0; r < 4; ++r) {
            const int lrow = wr * 64 + mi * 16 + quad * 4 + r;
            const int irow = row0 + lrow;
            float s = 0.f;
            #pragma unroll
            for (int ni = 0; ni < 4; ++ni) {
                const int jcol = col0 + wc * 64 + ni * 16 + cl;
                float e = __expf(TEMP_INV * acc[mi][ni][r]);
                e = (irow == jcol) ? 0.f : e;
                s += e;
                colacc[ni] += e;
            }
            s += __shfl_xor(s, 1);
            s += __shfl_xor(s, 2);
            s += __shfl_xor(s, 4);
            s += __shfl_xor(s, 8);
            if (cl == 0) atomicAdd(&rsum[lrow], s);
        }
    }
    if (!diag) {
        #pragma unroll
        for (int ni = 0; ni < 4; ++ni) {
            float c = colacc[ni];
            c += __shfl_xor(c, 16);
            c += __shfl_xor(c, 32);
            if (quad == 0) atomicAdd(&csum[wc * 64 + ni * 16 + cl], c);
        }
    }
    __syncthreads();
    if (tid < 128) {
        atomicAdd(&rowsum[row0 + tid], rsum[tid]);
        if (!diag) atomicAdd(&rowsum[col0 + tid], csum[tid]);
    }
}

// ---------------- kernel 3: finalize scalar loss ----------------
__global__ __launch_bounds__(256) void finalize_kernel(
    const float* __restrict__ rowsum, const float* __restrict__ pos,
    float* __restrict__ out) {
    const int t = threadIdx.x;
    float s = 0.f;
    for (int i = t; i < N_TOT; i += 256) s += logf(rowsum[i]);
    float p = 0.f;
    for (int i = t; i < B_ROWS; i += 256) p += pos[i];
    #pragma unroll
    for (int m = 32; m >= 1; m >>= 1) {
        s += __shfl_xor(s, m);
        p += __shfl_xor(p, m);
    }
    __shared__ float ws[4], wp[4];
    if ((t & 63) == 0) { ws[t >> 6] = s; wp[t >> 6] = p; }
    __syncthreads();
    if (t == 0) {
        float tot = ws[0] + ws[1] + ws[2] + ws[3];
        float ptot = wp[0] + wp[1] + wp[2] + wp[3];
        // loss = mean(log denom) - (2*posSum)/(temp*N)
        out[0] = tot / (float)N_TOT - ptot * (2.0f * TEMP_INV / (float)N_TOT);
    }
}

extern "C" void kernel_launch(void* const* d_in, const int* in_sizes, int n_in,
                              void* d_out, int out_size, void* d_ws, size_t ws_size,
                              hipStream_t stream) {
    const float* xi = (const float*)d_in[0];
    const float* xj = (const float*)d_in[1];
    float* out = (float*)d_out;
    char* ws = (char*)d_ws;

    unsigned short* z = (unsigned short*)ws;                       // 8 MB bf16
    float* rowsum = (float*)(ws + (size_t)N_TOT * D_DIM * 2);      // 32 KB
    float* pos = rowsum + N_TOT;                                   // 16 KB

    normpos_kernel<<<B_ROWS / 4, 256, 0, stream>>>(xi, xj, z, pos, rowsum);
    simrow_kernel<<<NTRI, 256, 0, stream>>>(z, rowsum);
    finalize_kernel<<<1, 256, 0, stream>>>(rowsum, pos, out);
}